// Round 10
// baseline (837.261 us; speedup 1.0000x reference)
//
#include <hip/hip_runtime.h>

#define KBINS  10
#define SBIN   100
#define BETA   0.9f
#define THR    1.0f
#define CDIV(a,b) (((a)+(b)-1)/(b))

// Padded spike layouts (halo zeros: 1 row top/bottom, 1 col left, 7 right):
//   spk1p [1000][ 4][52][192]   spk2p [1000][ 8][27][100]   spk3p [1000][16][15][54]
// Spike base pointers are raw+63 so the +1 halo offset makes wave stores
// 64B-aligned (Wp=192, HpWp mult of 64 for L1).

// ---------------------------------------------------------------------------
__global__ void k_zero16(float4* __restrict__ p, int n16) {
    int i = blockIdx.x * blockDim.x + threadIdx.x;
    if (i < n16) p[i] = make_float4(0.f, 0.f, 0.f, 0.f);
}

// ---------------------------------------------------------------------------
// Layer-1 conv for a t-chunk: 4 outputs (w) per thread, 4 couts.
// x (pre-offset) [tcount][100][368] -> c1 [tcount][4][50][184].
// ---------------------------------------------------------------------------
__global__ void k_conv1(const float* __restrict__ x,
                        const float* __restrict__ w1,
                        const float* __restrict__ b1,
                        float* __restrict__ c1, int tcount) {
    int n = blockIdx.x * blockDim.x + threadIdx.x;
    if (n >= tcount * 50 * 46) return;
    int wq  = n % 46;
    int tmp = n / 46;
    int h   = tmp % 50;
    int t   = tmp / 50;
    int w0  = wq * 4;

    const float* xt = x + (size_t)t * 36800;
    float rm2 = (h  < 49)  ? 1.f : 0.f;
    float cm8 = (w0 < 180) ? 1.f : 0.f;
    int   r2  = min(2 * h + 2, 99);
    int   cb  = 2 * w0;
    int   c8  = min(cb + 8, 367);

    const float* row0 = xt + (2 * h) * 368 + cb;
    const float* row1 = row0 + 368;
    const float* row2 = xt + r2 * 368 + cb;

    float tap[3][9];
    #pragma unroll
    for (int j = 0; j < 8; j++) {
        tap[0][j] = row0[j];
        tap[1][j] = row1[j];
        tap[2][j] = row2[j] * rm2;
    }
    tap[0][8] = xt[(2 * h) * 368 + c8] * cm8;
    tap[1][8] = xt[(2 * h + 1) * 368 + c8] * cm8;
    tap[2][8] = xt[r2 * 368 + c8] * (rm2 * cm8);

    float* ot = c1 + (size_t)t * 36800 + h * 184 + w0;
    #pragma unroll
    for (int co = 0; co < 4; co++) {
        float b = b1[co];
        float a0 = b, a1 = b, a2 = b, a3 = b;
        #pragma unroll
        for (int r = 0; r < 3; r++) {
            #pragma unroll
            for (int kw = 0; kw < 3; kw++) {
                float wv = w1[co * 9 + r * 3 + kw];
                a0 = fmaf(tap[r][0 + kw], wv, a0);
                a1 = fmaf(tap[r][2 + kw], wv, a1);
                a2 = fmaf(tap[r][4 + kw], wv, a2);
                a3 = fmaf(tap[r][6 + kw], wv, a3);
            }
        }
        *(float4*)(ot + (size_t)co * 9200) = make_float4(a0, a1, a2, a3);
    }
}

// ---------------------------------------------------------------------------
// Membrane scan over nbins bins of a t-chunk (cbuf is chunk-local t),
// PF=20 register double-buffer. m carried in mstate (init=1 -> m=0).
// ---------------------------------------------------------------------------
__global__ void k_scan(const float* __restrict__ cbuf,
                       unsigned char* __restrict__ spk,
                       float* __restrict__ skip,
                       float* __restrict__ mstate,
                       int C, int HW, int Win, int Wp, int HpWp,
                       int write_spk, int bin0, int nbins, int init) {
    const int PF = 20;
    int CHW = C * HW;
    int p = blockIdx.x * blockDim.x + threadIdx.x;
    if (p >= CHW) return;
    int c  = p / HW;
    int hw = p - c * HW;
    int h  = hw / Win, w = hw - h * Win;

    const size_t tstr = (size_t)C * HpWp;
    unsigned char* sp = spk + (size_t)bin0 * SBIN * tstr
                      + (size_t)c * HpWp + (h + 1) * Wp + (w + 1);

    float m = init ? 0.0f : mstate[p];
    float va[PF], vb[PF];
    #pragma unroll
    for (int j = 0; j < PF; j++) va[j] = cbuf[(size_t)j * CHW + p];

    const int T = nbins * SBIN;
    for (int k = 0; k < nbins; k++) {
        float s = 0.0f, q = 0.0f;
        for (int b = 0; b < SBIN / PF; b++) {
            int t0 = k * SBIN + b * PF;
            int tn = t0 + PF;
            bool more = (tn < T);
            #pragma unroll
            for (int j = 0; j < PF; j++)
                vb[j] = more ? cbuf[(size_t)(tn + j) * CHW + p] : 0.0f;
            #pragma unroll
            for (int j = 0; j < PF; j++) {
                m = fmaf(m, BETA, va[j]);
                float spv = (m - THR > 0.0f) ? 1.0f : 0.0f;
                m -= spv * THR;
                if (write_spk) sp[(size_t)(t0 + j) * tstr] = (unsigned char)spv;
                s += m;
                q = fmaf(m, m, q);
            }
            #pragma unroll
            for (int j = 0; j < PF; j++) va[j] = vb[j];
        }
        int g = bin0 + k;
        float mean = s * (1.0f / SBIN);
        float var  = q * (1.0f / SBIN) - mean * mean;
        float sd   = sqrtf(fmaxf(var, 1e-8f));
        skip[(size_t)(g * 2 * C + c) * HW + hw]     = mean;
        skip[(size_t)(g * 2 * C + C + c) * HW + hw] = sd;
    }
    mstate[p] = m;
}

// ---------------------------------------------------------------------------
// Stride-2 time-conv from padded u8 spikes, OW outputs/thread, COG couts.
// ---------------------------------------------------------------------------
template<int CIN, int COUT, int COG, int OW,
         int HOUT, int WOUT, int PADH, int HP, int WP>
__global__ void k_convs2(const unsigned char* __restrict__ spk,
                         const float* __restrict__ wt,
                         const float* __restrict__ bias,
                         float* __restrict__ out) {
    const int WQ = (WOUT + OW - 1) / OW;
    const int NT = 2 * OW + 1;
    int n = blockIdx.x * blockDim.x + threadIdx.x;
    if (n >= 1000 * HOUT * WQ) return;
    int wq  = n % WQ;
    int tmp = n / WQ;
    int h   = tmp % HOUT;
    int t   = tmp / HOUT;
    int cog = blockIdx.y;
    int w0  = wq * OW;

    const unsigned char* base = spk + (size_t)t * CIN * HP * WP
                              + (2 * h - PADH + 1) * WP + (2 * w0 + 1);

    float acc[OW][COG];
    #pragma unroll
    for (int q = 0; q < OW; q++)
        #pragma unroll
        for (int co = 0; co < COG; co++) acc[q][co] = bias[cog * COG + co];

    for (int ci = 0; ci < CIN; ci++) {
        const unsigned char* ic = base + (size_t)ci * HP * WP;
        float tap[3][NT];
        #pragma unroll
        for (int r = 0; r < 3; r++)
            #pragma unroll
            for (int j = 0; j < NT; j++)
                tap[r][j] = (float)ic[r * WP + j];
        #pragma unroll
        for (int co = 0; co < COG; co++) {
            const float* wc = wt + ((size_t)(cog * COG + co) * CIN + ci) * 9;
            #pragma unroll
            for (int r = 0; r < 3; r++)
                #pragma unroll
                for (int kw = 0; kw < 3; kw++) {
                    float wv = wc[r * 3 + kw];
                    #pragma unroll
                    for (int q = 0; q < OW; q++)
                        acc[q][co] = fmaf(tap[r][2 * q + kw], wv, acc[q][co]);
                }
        }
    }

    float* ot = out + ((size_t)t * COUT + cog * COG) * (HOUT * WOUT) + h * WOUT + w0;
    #pragma unroll
    for (int co = 0; co < COG; co++) {
        float* oc = ot + (size_t)co * (HOUT * WOUT);
        if constexpr (OW == 4) {
            *(float4*)oc = make_float4(acc[0][co], acc[1][co], acc[2][co], acc[3][co]);
        } else {
            if (w0 + 2 <= WOUT) *(float2*)oc = make_float2(acc[0][co], acc[1][co]);
            else                oc[0] = acc[0][co];
        }
    }
}

// ---------------------------------------------------------------------------
// Bilinear upsample (JAX half-pixel, edge-clamp) + channel concat.
// ---------------------------------------------------------------------------
__global__ void k_up_cat(const float* __restrict__ up_src, int Cup, int Hi, int Wi,
                         const float* __restrict__ skip, int Cskip,
                         float* __restrict__ out, int Ho, int Wo) {
    int total = (Cup + Cskip) * Ho * Wo;
    int n = blockIdx.x * blockDim.x + threadIdx.x;
    if (n >= total) return;
    int w   = n % Wo;
    int tmp = n / Wo;
    int h   = tmp % Ho;
    int c   = tmp / Ho;
    float v;
    if (c < Cup) {
        float ph = (h + 0.5f) * (float)Hi / (float)Ho - 0.5f;
        float pw = (w + 0.5f) * (float)Wi / (float)Wo - 0.5f;
        float fh = floorf(ph), fw = floorf(pw);
        int h0 = (int)fh, w0 = (int)fw;
        float ah = ph - fh, aw = pw - fw;
        int h0c = min(max(h0, 0), Hi - 1), h1c = min(max(h0 + 1, 0), Hi - 1);
        int w0c = min(max(w0, 0), Wi - 1), w1c = min(max(w0 + 1, 0), Wi - 1);
        const float* sc = up_src + (size_t)c * Hi * Wi;
        float v00 = sc[h0c * Wi + w0c], v01 = sc[h0c * Wi + w1c];
        float v10 = sc[h1c * Wi + w0c], v11 = sc[h1c * Wi + w1c];
        v = (1.0f - ah) * ((1.0f - aw) * v00 + aw * v01)
          + ah * ((1.0f - aw) * v10 + aw * v11);
    } else {
        v = skip[(size_t)(c - Cup) * Ho * Wo + h * Wo + w];
    }
    out[n] = v;
}

// ---------------------------------------------------------------------------
// Decoder split-K conv, templated CS/COG. part[chunk][Cout][HW].
// ---------------------------------------------------------------------------
template<int CIN, int CS, int COG>
__global__ void k_dconv(const float* __restrict__ in,
                        const float* __restrict__ wt,
                        float* __restrict__ part,
                        int Cout, int H, int W) {
    int HW  = H * W;
    int pix = blockIdx.x * blockDim.x + threadIdx.x;
    if (pix >= HW) return;
    int co0   = blockIdx.y * COG;
    int chunk = blockIdx.z;
    int h = pix / W, w = pix - h * W;

    int off[9]; float msk[9];
    #pragma unroll
    for (int kh = 0; kh < 3; kh++) {
        int r = h + kh - 1;
        bool rok = (r >= 0) && (r < H);
        int rc = rok ? r : 0;
        #pragma unroll
        for (int kw = 0; kw < 3; kw++) {
            int cc = w + kw - 1;
            bool cok = (cc >= 0) && (cc < W);
            int ccc = cok ? cc : 0;
            off[kh * 3 + kw] = rc * W + ccc;
            msk[kh * 3 + kw] = (rok && cok) ? 1.0f : 0.0f;
        }
    }

    const float* ibase = in + (size_t)chunk * CS * HW;
    const float* wbase = wt + ((size_t)co0 * CIN + (size_t)chunk * CS) * 9;

    float acc[COG];
    #pragma unroll
    for (int co = 0; co < COG; co++) acc[co] = 0.0f;

    #pragma unroll 8
    for (int ci = 0; ci < CS; ci++) {
        const float* ic = ibase + (size_t)ci * HW;
        float tap[9];
        #pragma unroll
        for (int j = 0; j < 9; j++)
            tap[j] = msk[j] * ic[off[j]];
        #pragma unroll
        for (int co = 0; co < COG; co++) {
            const float* wc = wbase + ((size_t)co * CIN + ci) * 9;
            #pragma unroll
            for (int j = 0; j < 9; j++)
                acc[co] = fmaf(tap[j], wc[j], acc[co]);
        }
    }

    float* pp = part + ((size_t)chunk * Cout + co0) * HW + pix;
    #pragma unroll
    for (int co = 0; co < COG; co++) pp[(size_t)co * HW] = acc[co];
}

__global__ void k_reduce_relu(const float* __restrict__ part,
                              const float* __restrict__ bias,
                              float* __restrict__ out,
                              int Cout, int HW, int nchunks) {
    int n = blockIdx.x * blockDim.x + threadIdx.x;
    if (n >= Cout * HW) return;
    int co = n / HW;
    float acc = bias[co];
    for (int c = 0; c < nchunks; c++)
        acc += part[(size_t)c * Cout * HW + n];
    out[n] = fmaxf(acc, 0.0f);
}

// ---------------------------------------------------------------------------
__global__ void k_final(const float* __restrict__ d1,
                        const float* __restrict__ wo,
                        const float* __restrict__ bo,
                        float* __restrict__ out) {
    int n = blockIdx.x * blockDim.x + threadIdx.x;
    if (n >= 36800) return;
    int w = n % 368, h = n / 368;
    float ph = (h + 0.5f) * 0.5f - 0.5f;
    float pw = (w + 0.5f) * 0.5f - 0.5f;
    float fh = floorf(ph), fw = floorf(pw);
    int h0 = (int)fh, w0 = (int)fw;
    float ah = ph - fh, aw = pw - fw;
    int h0c = min(max(h0, 0), 49),  h1c = min(max(h0 + 1, 0), 49);
    int w0c = min(max(w0, 0), 183), w1c = min(max(w0 + 1, 0), 183);
    float acc = bo[0];
    #pragma unroll
    for (int c = 0; c < 8; c++) {
        const float* sc = d1 + c * 9200;
        float v00 = sc[h0c * 184 + w0c], v01 = sc[h0c * 184 + w1c];
        float v10 = sc[h1c * 184 + w0c], v11 = sc[h1c * 184 + w1c];
        float v = (1.0f - ah) * ((1.0f - aw) * v00 + aw * v01)
                + ah * ((1.0f - aw) * v10 + aw * v11);
        acc = fmaf(wo[c], v, acc);
    }
    out[n] = acc;
}

// ---------------------------------------------------------------------------
extern "C" void kernel_launch(void* const* d_in, const int* in_sizes, int n_in,
                              void* d_out, int out_size, void* d_ws, size_t ws_size,
                              hipStream_t stream) {
    (void)in_sizes; (void)n_in; (void)out_size; (void)ws_size;
    const float* x   = (const float*)d_in[0];
    const float* w1  = (const float*)d_in[1];
    const float* b1  = (const float*)d_in[2];
    const float* w2  = (const float*)d_in[3];
    const float* b2  = (const float*)d_in[4];
    const float* w3  = (const float*)d_in[5];
    const float* b3  = (const float*)d_in[6];
    const float* w4  = (const float*)d_in[7];
    const float* b4  = (const float*)d_in[8];
    const float* dw4 = (const float*)d_in[9];
    const float* db4 = (const float*)d_in[10];
    const float* dw3 = (const float*)d_in[11];
    const float* db3 = (const float*)d_in[12];
    const float* dw2 = (const float*)d_in[13];
    const float* db2 = (const float*)d_in[14];
    const float* dw1 = (const float*)d_in[15];
    const float* db1 = (const float*)d_in[16];
    const float* wo  = (const float*)d_in[17];
    const float* bo  = (const float*)d_in[18];
    float* out = (float*)d_out;

    // ---- workspace ----
    char* ws = (char*)d_ws;
    size_t off = 0;
    auto alloc = [&](size_t bytes) -> void* {
        void* p = ws + off;
        off += (bytes + 255) & ~(size_t)255;
        return p;
    };
    float* cbuf = (float*)alloc(73600000);                    // 500-t c1 chunk / c2 / c3 / c4
    unsigned char* spk1r = (unsigned char*)alloc(39936000 + 256);
    unsigned char* spk2r = (unsigned char*)alloc(21600000 + 256);
    unsigned char* spk3r = (unsigned char*)alloc(12960000 + 256);
    unsigned char* spk1p = spk1r + 63;   // +63: wave stores at (w+1) are 64B-aligned
    unsigned char* spk2p = spk2r + 63;
    unsigned char* spk3p = spk3r + 63;
    float* skip0 = (float*)alloc(2944000);
    float* skip1 = (float*)alloc(1472000);
    float* skip2 = (float*)alloc(765440);
    float* skip3 = (float*)alloc(412160);
    float* msS   = (float*)alloc(147200);
    // decoder buffers alias cbuf (dead after encoder)
    char* dec = (char*)cbuf;
    size_t doff = 0;
    auto dalloc = [&](size_t bytes) -> void* {
        void* p = dec + doff;
        doff += (bytes + 255) & ~(size_t)255;
        return p;
    };
    float* d4   = (float*)dalloc(10304u * 4);
    float* d3   = (float*)dalloc(19136u * 4);
    float* d2   = (float*)dalloc(36800u * 4);
    float* d1   = (float*)dalloc(73600u * 4);
    float* cat3 = (float*)dalloc(229632u * 4);
    float* cat2 = (float*)dalloc(441600u * 4);
    float* cat1 = (float*)dalloc(883200u * 4);
    float* part = (float*)dalloc(230400u * 4);

    const int BS  = 256;
    const int SBS = 64;

    // zero spike buffers incl. halos (contiguous raw span)
    {
        size_t nb = (39936000 + 256) + (21600000 + 256) + (12960000 + 256);
        int n16 = (int)(nb / 16);
        k_zero16<<<CDIV(n16, BS), BS, 0, stream>>>((float4*)spk1r, n16);
    }

    // ---- layer 1: 2 chunks x 500 steps (c1 chunk 73.6 MB stays L3-hot) ----
    for (int q = 0; q < 2; q++) {
        k_conv1<<<CDIV(500 * 50 * 46, BS), BS, 0, stream>>>(
            x + (size_t)q * 500 * 36800, w1, b1, cbuf, 500);
        k_scan<<<CDIV(36800, SBS), SBS, 0, stream>>>(
            cbuf, spk1p, skip0, msS, 4, 9200, 184, 192, 52 * 192,
            1, 5 * q, 5, (q == 0) ? 1 : 0);
    }

    // ---- layers 2-4: full-T (c2/c3/c4 each fit L3) ----
    k_convs2<4, 8, 8, 4, 25, 92, 0, 52, 192>
        <<<dim3(CDIV(1000 * 25 * 23, BS), 1), BS, 0, stream>>>(spk1p, w2, b2, cbuf);
    k_scan<<<CDIV(18400, SBS), SBS, 0, stream>>>(cbuf, spk2p, skip1, msS,
                                                 8, 2300, 92, 100, 27 * 100, 1, 0, 10, 1);

    k_convs2<8, 16, 16, 2, 13, 46, 1, 27, 100>
        <<<dim3(CDIV(1000 * 13 * 23, BS), 1), BS, 0, stream>>>(spk2p, w3, b3, cbuf);
    k_scan<<<CDIV(9568, SBS), SBS, 0, stream>>>(cbuf, spk3p, skip2, msS,
                                                16, 598, 46, 54, 15 * 54, 1, 0, 10, 1);

    k_convs2<16, 32, 16, 2, 7, 23, 1, 15, 54>
        <<<dim3(CDIV(1000 * 7 * 12, BS), 2), BS, 0, stream>>>(spk3p, w4, b4, cbuf);
    k_scan<<<CDIV(5152, SBS), SBS, 0, stream>>>(cbuf, spk1p /*unused*/, skip3, msS,
                                                32, 161, 23, 31, 9 * 31, 0, 0, 10, 1);

    // ---- decoder (R8 structure) ----
    {   // L4
        dim3 g(CDIV(161, 64), 16, 20);
        k_dconv<640, 32, 4><<<g, 64, 0, stream>>>(skip3, dw4, part, 64, 7, 23);
        k_reduce_relu<<<CDIV(64 * 161, BS), BS, 0, stream>>>(part, db4, d4, 64, 161, 20);
    }
    {   // L3
        k_up_cat<<<CDIV(384 * 598, BS), BS, 0, stream>>>(d4, 64, 7, 23,
                                                         skip2, 320, cat3, 13, 46);
        dim3 g(CDIV(598, 64), 8, 12);
        k_dconv<384, 32, 4><<<g, 64, 0, stream>>>(cat3, dw3, part, 32, 13, 46);
        k_reduce_relu<<<CDIV(32 * 598, BS), BS, 0, stream>>>(part, db3, d3, 32, 598, 12);
    }
    {   // L2
        k_up_cat<<<CDIV(192 * 2300, BS), BS, 0, stream>>>(d3, 32, 13, 46,
                                                          skip1, 160, cat2, 25, 92);
        dim3 g(CDIV(2300, 128), 4, 6);
        k_dconv<192, 32, 4><<<g, 128, 0, stream>>>(cat2, dw2, part, 16, 25, 92);
        k_reduce_relu<<<CDIV(16 * 2300, BS), BS, 0, stream>>>(part, db2, d2, 16, 2300, 6);
    }
    {   // L1
        k_up_cat<<<CDIV(96 * 9200, BS), BS, 0, stream>>>(d2, 16, 25, 92,
                                                         skip0, 80, cat1, 50, 184);
        dim3 g(CDIV(9200, BS), 2, 3);
        k_dconv<96, 32, 4><<<g, BS, 0, stream>>>(cat1, dw1, part, 8, 50, 184);
        k_reduce_relu<<<CDIV(8 * 9200, BS), BS, 0, stream>>>(part, db1, d1, 8, 9200, 3);
    }
    k_final<<<CDIV(36800, BS), BS, 0, stream>>>(d1, wo, bo, out);
}